// Round 15
// baseline (83.597 us; speedup 1.0000x reference)
//
#include <hip/hip_runtime.h>
#include <hip/hip_bf16.h>
#include <stdint.h>

// Fused NCA step via MATRIX CORES — verified-primitives-only build.
// perception(4 fixed 3x3, wrap) -> 1x1 conv 32->16 +b+ReLU -> 1x1 conv 16->8
// -> x + y*mask.
// R15 = R14 (80.7us) with VALU-instruction cuts only (no structural change):
//  - __float22bfloat162_rn (HW v_cvt_pk_bf16_f32, RNE == R14's manual RNE)
//    replaces the ~8-VALU bit-twiddle pkbf: 6 packs/iter at 1 VALU each.
//  - i-loop fully unrolled: per-iter LDS offsets differ by 256 B -> become
//    ds_read immediate offsets; addressing VALU collapses. VGPR cap 128
//    (2 blocks/CU, 4 waves/SIMD) leaves room.
//  - mask de-staged: 8 prologue dword loads/lane (L2-hot), -4KB LDS, and the
//    staging loop becomes shift-indexed (kills /6 %6 magic-mul chains).

constexpr int B = 16, C = 8, H = 512, W = 512, HID = 16;
constexpr int HW = H * W;

// LDS geometry (floats). Rows halo-padded: [pad3][lhalo][512 data][rhalo]
// data col c at idx c+4; left halo idx3 = col 511; right halo idx516 = col 0.
constexpr int ROWF = 520;            // 2080 B, 16B-aligned rows
constexpr int CHF  = 4 * ROWF + 8;   // 2088: +8 pad spreads channels over banks
constexpr int LDSF = 8 * CHF;        // 16704 floats = 66816 B

typedef __attribute__((ext_vector_type(8))) short bf16x8;
typedef __attribute__((ext_vector_type(4))) float f32x4;
typedef const __attribute__((address_space(1))) void* as1cp;
typedef __attribute__((address_space(3))) void* as3p;

__device__ __host__ inline uint32_t bf16rne(float f) {   // result in low 16
    const uint32_t u = __float_as_uint(f);
    return (u + 0x7fffu + ((u >> 16) & 1u)) >> 16;
}
__device__ inline float bf16tof(uint32_t hs) { return __uint_as_float(hs << 16); }

// pack two floats to {bf16 lo, bf16 hi} via HW cvt_pk (RNE)
__device__ inline uint32_t pk2(float a, float b) {
    union { __hip_bfloat162 h; uint32_t u; } r;
    r.h = __float22bfloat162_rn(make_float2(a, b));
    return r.u;
}

// d_ws layout (u32 units):
//  [0..255]   W1eff hi A-frag: lane t holds elems j=0..7 of (row=t&15, grp=t>>4)
//  [256..511] W1eff lo A-frag
//  [512..767] W2 A-frag, K=32 zero-padded: j<4 -> w2[och=t&15][(t>>4)*4+j]
//             (0 for och>=8), j>=4 -> 0
//  [768..783] bias (f32)
__global__ void repack(const float* __restrict__ w1w,
                       const float* __restrict__ w1b,
                       const float* __restrict__ w2w,
                       float* __restrict__ wdf) {
    uint32_t* wd = (uint32_t*)wdf;
    const int t = threadIdx.x;
    if (t >= 64) return;
    const int h = t & 15, kg = t >> 4;
    uint32_t whi[4] = {0, 0, 0, 0}, wlo[4] = {0, 0, 0, 0}, w2f[4] = {0, 0, 0, 0};
    for (int j = 0; j < 8; ++j) {
        const int k = kg * 8 + j, ch = k >> 2, f = k & 3;
        const float* wr = w1w + h * 32 + ch * 4;
        // fold perception scales + lap's -ident into W1
        const float we = (f == 0) ? (wr[0] - wr[3])
                       : (f == 3) ? wr[3] * 0.0625f
                                  : wr[f] * 0.125f;
        const uint32_t hs = bf16rne(we);
        const uint32_t ls = bf16rne(we - bf16tof(hs));
        whi[j >> 1] |= hs << (16 * (j & 1));
        wlo[j >> 1] |= ls << (16 * (j & 1));
    }
    for (int j = 0; j < 4; ++j) {        // conv2 frag: j>=4 stays zero
        const float v = (h < 8) ? w2w[h * 16 + kg * 4 + j] : 0.0f;
        w2f[j >> 1] |= bf16rne(v) << (16 * (j & 1));
    }
    for (int q = 0; q < 4; ++q) {
        wd[t * 4 + q]       = whi[q];
        wd[256 + t * 4 + q] = wlo[q];
        wd[512 + t * 4 + q] = w2f[q];
    }
    if (t < 16) wdf[768 + t] = w1b[t];
}

__global__ __launch_bounds__(512, 4) void nca_step_kernel(
    const float* __restrict__ x,
    const int*   __restrict__ mask,
    float*       __restrict__ out,
    const float* __restrict__ wdf)
{
    __shared__ float S[LDSF];

    // block = one row PAIR; XCD-bijective swizzle (4096 = 8 * 512)
    const int bid = blockIdx.x;
    const int l   = (bid & 7) * 512 + (bid >> 3);
    const int b   = l >> 8;
    const int y0  = (l & 255) << 1;

    const int tid  = threadIdx.x;
    const int lane = tid & 63;
    const int wv   = tid >> 6;            // wave 0..7

    const float* xb = x + (size_t)b * C * HW;
    const int*   mb = mask + (size_t)b * HW;

    const int rel = wv >> 2;              // 0: row y0, 1: row y1
    const int y   = y0 + rel;
    const int grp = lane >> 4;            // lane-group: channels 2grp, 2grp+1
    const int p   = lane & 15;            // px within group
    const int chA = grp * 2;

    // mask: 8 direct dword loads (one per i-iter), issued first, L2-hot
    int msk[8];
#pragma unroll
    for (int i = 0; i < 8; ++i)
        msk[i] = mb[y * W + ((wv & 3) + 4 * i) * 16 + p];

    // per-lane constant fragments (same for every wave)
    union { uint4 u; bf16x8 v; } whiU, wloU, w2U;
    whiU.u = ((const uint4*)wdf)[lane];
    wloU.u = ((const uint4*)wdf)[64 + lane];
    w2U.u  = ((const uint4*)wdf)[128 + lane];
    const f32x4 bias4 = ((const f32x4*)(wdf + 768))[lane >> 4];

    // ---- stage: 8ch x 4 rows (y0-1..y0+2), 64 x 1KB DMAs, 8 per wave ----
    // wave wv owns (rs = wv>>1, hf = wv&1) for all 8 channels (pure shifts)
    {
        const int rs   = (wv >> 1) & 3;
        const int hf   = wv & 1;
        const int grow = (y0 - 1 + rs) & (H - 1);
        const int goff = grow * W + hf * 256 + lane * 4;
        const int loff = rs * ROWF + 4 + hf * 256;
#pragma unroll
        for (int ch = 0; ch < 8; ++ch) {
            const float* src = xb + ch * HW + goff;
            float* dst = S + ch * CHF + loff;
            __builtin_amdgcn_global_load_lds((as1cp)src, (as3p)dst, 16, 0, 0);
        }
    }
    __syncthreads();                      // drains the DMAs
    if (tid < 64) {                       // halo fill (wrap columns)
        const int r = tid >> 1;
        float* rb = S + (r >> 2) * CHF + (r & 3) * ROWF;
        if (tid & 1) rb[516] = rb[4];     // right halo = col 0
        else         rb[3]   = rb[515];   // left halo  = col 511
    }
    __syncthreads();

    float* ob = out + (size_t)b * C * HW;

    // ---- compute: wave wv -> row y0+rel, px groups (wv&3)+4i ----
#pragma unroll
    for (int i = 0; i < 8; ++i) {
        const int g  = (wv & 3) + i * 4;
        const int px = g * 16 + p;
        const int ci = px + 3;            // LDS idx of col px-1

        // features in fragment element order: j=0..3 ch=chA, j=4..7 ch=chA+1,
        // each {ident, sx_raw, sy_raw, lap_raw} (scales folded into W1)
        float f_[8];
#pragma unroll
        for (int cc = 0; cc < 2; ++cc) {
            const float* R0 = S + (chA + cc) * CHF + rel * ROWF + ci;
            const float* R1 = R0 + ROWF;
            const float* R2 = R1 + ROWF;
            const float a0 = R0[0], a1 = R0[1], a2 = R0[2];
            const float b0 = R1[0], b1 = R1[1], b2 = R1[2];
            const float c0 = R2[0], c1 = R2[1], c2 = R2[2];
            const float s0 = fmaf(2.f, b0, a0 + c0);
            const float s1 = fmaf(2.f, b1, a1 + c1);
            const float s2 = fmaf(2.f, b2, a2 + c2);
            const float d0 = c0 - a0, d1 = c1 - a1, d2 = c2 - a2;
            f_[cc * 4 + 0] = b1;
            f_[cc * 4 + 1] = s2 - s0;
            f_[cc * 4 + 2] = fmaf(2.f, d1, d0 + d2);
            f_[cc * 4 + 3] = fmaf(2.f, s1, s0 + s2);
        }

        // single-bf16 feature fragment: 4x HW cvt_pk
        union { uint32_t u[4]; bf16x8 v; } bh = {{
            pk2(f_[0], f_[1]), pk2(f_[2], f_[3]),
            pk2(f_[4], f_[5]), pk2(f_[6], f_[7])}};

        // conv1: W*F = (Whi + Wlo)*F   (W split exact; bias preloaded in C)
        f32x4 acc = bias4;
        acc = __builtin_amdgcn_mfma_f32_16x16x32_bf16(whiU.v, bh.v, acc, 0, 0, 0);
        acc = __builtin_amdgcn_mfma_f32_16x16x32_bf16(wloU.v, bh.v, acc, 0, 0, 0);

        // conv2 via the SAME verified K=32 builtin, zero-padded fragments:
        // B elems j<4 = relu(acc[j]) (= hid 4*grp+j), j>=4 = 0; A likewise.
        union { uint32_t u[4]; bf16x8 v; } b2 = {{
            pk2(fmaxf(acc[0], 0.f), fmaxf(acc[1], 0.f)),
            pk2(fmaxf(acc[2], 0.f), fmaxf(acc[3], 0.f)), 0, 0}};
        f32x4 d2 = {0.f, 0.f, 0.f, 0.f};
        d2 = __builtin_amdgcn_mfma_f32_16x16x32_bf16(w2U.v, b2.v, d2, 0, 0, 0);

        // epilogue: lanes 0..31 hold och=(lane>>4)*4+r (rows 8..15 are pad)
        if (lane < 32) {
            const float mfv = (float)msk[i];
            const int och0 = grp * 4;
            float* op = ob + y * W + px;
#pragma unroll
            for (int r = 0; r < 4; ++r) {
                const float xv =
                    S[(och0 + r) * CHF + (rel + 1) * ROWF + 4 + px];
                op[(och0 + r) * HW] = fmaf(d2[r], mfv, xv);
            }
        }
    }
}

extern "C" void kernel_launch(void* const* d_in, const int* in_sizes, int n_in,
                              void* d_out, int out_size, void* d_ws, size_t ws_size,
                              hipStream_t stream) {
    const float* x    = (const float*)d_in[0];
    const float* w1w  = (const float*)d_in[1];
    const float* w1b  = (const float*)d_in[2];
    const float* w2w  = (const float*)d_in[3];
    const int*   mask = (const int*)d_in[4];
    float* out = (float*)d_out;
    float* wdf = (float*)d_ws;            // 3.1 KB of fragment scratch

    hipLaunchKernelGGL(repack, dim3(1), dim3(64), 0, stream,
                       w1w, w1b, w2w, wdf);
    hipLaunchKernelGGL(nca_step_kernel, dim3(B * H / 2), dim3(512), 0, stream,
                       x, mask, out, wdf);
}